// Round 11
// baseline (2406.725 us; speedup 1.0000x reference)
//
#include <hip/hip_runtime.h>
#include <math.h>

// DGCNN_Reg: B=8, N=4096, k=20.
// Point-major layouts: X[p][c], U[p][o], T[p][o] with p = b*4096 + n.
// Edge conv factorized: y[o,n,k] = U[idx[n,k]][o] + T[n][o];
// BN+LeakyReLU (scale>0) commutes with max over k.
// R11 (single change vs R10): pd GEMM moved to MFMA via bf16x3 split
// (hi*hi + hi*lo + lo*hi; dropped lo*lo ~2^-18). sqnorm_cvt emits bf16
// hi/lo planes (aliased into X4 slab, dead until layer-4 gather). xx chain
// and all other kernels byte-identical to R10.

constexpr int NPT = 4096;
constexpr int BATCH = 8;
constexpr int PTS = BATCH * NPT;   // 32768
constexpr float EPS = 1e-5f;
#define KC 16
#define PAD 68    // 64-wide tiles: 68 mod 32 = 4 -> conflict-free staging
#define PADB 132  // 128-wide tiles: 132 mod 32 = 4 -> conflict-free staging
#define NEG_INF -3.4e38f

typedef __attribute__((ext_vector_type(8))) short bf16x8;
typedef __attribute__((ext_vector_type(4))) float f32x4;

__device__ __forceinline__ ushort f2bf(float f) {      // RNE truncate to bf16
    unsigned u = __float_as_uint(f);
    return (ushort)((u + 0x7fffu + ((u >> 16) & 1u)) >> 16);
}

// ---------------- sum of squares per point (layer 1; xx only) ----------------
__global__ __launch_bounds__(256) void sqnorm(const float* __restrict__ X,
                                              float* __restrict__ xx, int C) {
    int p = blockIdx.x * 256 + threadIdx.x;
    if (p >= PTS) return;
    float s = 0.f;
    const float* row = X + (size_t)p * C;
    for (int c = 0; c < C; ++c) s = fmaf(row[c], row[c], s);
    xx[p] = s;
}

// ---------------- sqnorm + bf16 hi/lo split planes (layers 2-4) ----------------
// xx FMA chain identical to sqnorm (bit-exact canary).
__global__ __launch_bounds__(256) void sqnorm_cvt(const float* __restrict__ X,
                                                  float* __restrict__ xx,
                                                  ushort* __restrict__ Xh,
                                                  ushort* __restrict__ Xl, int C) {
    int p = blockIdx.x * 256 + threadIdx.x;
    if (p >= PTS) return;
    const float* row = X + (size_t)p * C;
    ushort* hr = Xh + (size_t)p * C;
    ushort* lr = Xl + (size_t)p * C;
    float s = 0.f;
    for (int c = 0; c < C; ++c) {
        float v = row[c];
        s = fmaf(v, v, s);
        ushort hb = f2bf(v);
        float hf = __uint_as_float((unsigned)hb << 16);
        hr[c] = hb;
        lr[c] = f2bf(v - hf);
    }
    xx[p] = s;
}

// ---------------- symmetric pd via MFMA (bf16x3), 128x128 tiles, upper tri ------
// 4 waves, each owns a 64x64 quadrant (wr=wid>>1, wc=wid&1). K-step 32.
// A-frag: lane holds Xrow[rt + (lane&15)][k=(lane>>4)*8..+8]; B-frag same from
// col block (X.X^T symmetry -> both operands read point rows). C/D: col=lane&15,
// row=(lane>>4)*4+reg [m89]. LDS rows padded to 40 ushorts -> 2-way banks.
__global__ __launch_bounds__(256) void pd_mfma(const ushort* __restrict__ Xh,
                                               const ushort* __restrict__ Xl,
                                               const float* __restrict__ xx,
                                               float* __restrict__ pd0,
                                               int C, int bbase, size_t pdstride) {
    int b = bbase + blockIdx.y;
    float* pd = pd0 + (size_t)blockIdx.y * pdstride;
    int bid = blockIdx.x;
    int ti = 0, rem = bid;
    while (rem >= 32 - ti) { rem -= 32 - ti; ++ti; }
    int tj = ti + rem;
    int rowbase = ti * 128, colbase = tj * 128;
    int p0 = b * NPT;

    __shared__ ushort Rh[128][40], Rl[128][40], Ch[128][40], Cl[128][40];
    __shared__ float xxr[128], xxc[128];
    int tid = threadIdx.x;
    int lane = tid & 63, wid = tid >> 6;
    int wr = wid >> 1, wc = wid & 1;

    if (tid < 128) xxr[tid] = xx[p0 + rowbase + tid];
    else           xxc[tid - 128] = xx[p0 + colbase + tid - 128];

    const int pt = tid >> 1;            // staging point 0..127
    const int co = (tid & 1) * 16;      // staging channel base {0,16}
    size_t rrow = (size_t)(p0 + rowbase + pt) * C;
    size_t crow = (size_t)(p0 + colbase + pt) * C;

    f32x4 z = {0.f, 0.f, 0.f, 0.f};
    f32x4 acc[4][4];
#pragma unroll
    for (int sr = 0; sr < 4; ++sr)
#pragma unroll
        for (int sc = 0; sc < 4; ++sc) acc[sr][sc] = z;

    for (int c0 = 0; c0 < C; c0 += 32) {
        uint4 vrh0 = *(const uint4*)&Xh[rrow + c0 + co];
        uint4 vrh1 = *(const uint4*)&Xh[rrow + c0 + co + 8];
        uint4 vrl0 = *(const uint4*)&Xl[rrow + c0 + co];
        uint4 vrl1 = *(const uint4*)&Xl[rrow + c0 + co + 8];
        uint4 vch0 = *(const uint4*)&Xh[crow + c0 + co];
        uint4 vch1 = *(const uint4*)&Xh[crow + c0 + co + 8];
        uint4 vcl0 = *(const uint4*)&Xl[crow + c0 + co];
        uint4 vcl1 = *(const uint4*)&Xl[crow + c0 + co + 8];
        __syncthreads();                 // prior K-step's LDS reads done
        *(uint4*)&Rh[pt][co] = vrh0; *(uint4*)&Rh[pt][co + 8] = vrh1;
        *(uint4*)&Rl[pt][co] = vrl0; *(uint4*)&Rl[pt][co + 8] = vrl1;
        *(uint4*)&Ch[pt][co] = vch0; *(uint4*)&Ch[pt][co + 8] = vch1;
        *(uint4*)&Cl[pt][co] = vcl0; *(uint4*)&Cl[pt][co + 8] = vcl1;
        __syncthreads();
        bf16x8 ah[4], al[4], bh[4], bl[4];
#pragma unroll
        for (int s = 0; s < 4; ++s) {
            int ar = wr * 64 + s * 16 + (lane & 15);
            int br = wc * 64 + s * 16 + (lane & 15);
            int ko = (lane >> 4) * 8;
            ah[s] = *(const bf16x8*)&Rh[ar][ko];
            al[s] = *(const bf16x8*)&Rl[ar][ko];
            bh[s] = *(const bf16x8*)&Ch[br][ko];
            bl[s] = *(const bf16x8*)&Cl[br][ko];
        }
#pragma unroll
        for (int sr = 0; sr < 4; ++sr)
#pragma unroll
            for (int sc = 0; sc < 4; ++sc) {
                acc[sr][sc] = __builtin_amdgcn_mfma_f32_16x16x32_bf16(ah[sr], bh[sc], acc[sr][sc], 0, 0, 0);
                acc[sr][sc] = __builtin_amdgcn_mfma_f32_16x16x32_bf16(ah[sr], bl[sc], acc[sr][sc], 0, 0, 0);
                acc[sr][sc] = __builtin_amdgcn_mfma_f32_16x16x32_bf16(al[sr], bh[sc], acc[sr][sc], 0, 0, 0);
            }
    }

    int rl0 = wr * 64 + (lane >> 4) * 4;
    int ml  = wc * 64 + (lane & 15);
    // normal store: pd[r][m] = 2*acc - xx[r] - xx[m]
#pragma unroll
    for (int sr = 0; sr < 4; ++sr)
#pragma unroll
        for (int sc = 0; sc < 4; ++sc) {
            int mm = ml + sc * 16;
            float xm = xxc[mm];
#pragma unroll
            for (int reg = 0; reg < 4; ++reg) {
                int rr = rl0 + sr * 16 + reg;
                float o = 2.f * acc[sr][sc][reg] - xxr[rr] - xm;
                pd[(size_t)(rowbase + rr) * NPT + colbase + mm] = o;
            }
        }
    // mirrored store: pd[m][r] = 2*acc - xx[m] - xx[r]
    if (ti != tj) {
#pragma unroll
        for (int sr = 0; sr < 4; ++sr) {
            int rr0 = rl0 + sr * 16;
#pragma unroll
            for (int sc = 0; sc < 4; ++sc) {
                int mm = ml + sc * 16;
                float xm = xxc[mm];
                float4 o;
                o.x = 2.f * acc[sr][sc][0] - xm - xxr[rr0 + 0];
                o.y = 2.f * acc[sr][sc][1] - xm - xxr[rr0 + 1];
                o.z = 2.f * acc[sr][sc][2] - xm - xxr[rr0 + 2];
                o.w = 2.f * acc[sr][sc][3] - xm - xxr[rr0 + 3];
                *(float4*)&pd[(size_t)(colbase + mm) * NPT + rowbase + rr0] = o;
            }
        }
    }
}

// ---------------- shared topk core: per-lane top-2 + lazy rescan ----------------
// v[64] per lane; global col of v[j] = (j>>2)*256 + lane*4 + (j&3).
__device__ __forceinline__ void topk_core(float (&v)[64], int lane, int b,
                                          int* __restrict__ op) {
    float m1 = NEG_INF, m2 = NEG_INF;
    int j1 = 0, j2 = 0;
#pragma unroll
    for (int j = 0; j < 64; ++j) {
        float vv = v[j];
        bool c1 = vv > m1;          // strict > : earlier (smaller) j wins ties
        bool c2 = vv > m2;
        m2 = c1 ? m1 : (c2 ? vv : m2);
        j2 = c1 ? j1 : (c2 ? j : j2);
        m1 = c1 ? vv : m1;
        j1 = c1 ? j : j1;
    }
    bool have2 = true;
    unsigned long long remM = 0ull;
    for (int t = 0; t < 20; ++t) {
        int g1 = ((j1 >> 2) << 8) + (lane << 2) + (j1 & 3);
        float bv = m1; int gi = g1;
#pragma unroll
        for (int s = 1; s < 64; s <<= 1) {
            float ov = __shfl_xor(bv, s);
            int og = __shfl_xor(gi, s);
            if (ov > bv || (ov == bv && og < gi)) { bv = ov; gi = og; }
        }
        if (lane == 0) op[t] = b * NPT + gi;
        bool needscan = false;
        if (gi == g1) {             // g1 encodes lane -> unique; this lane won
            remM |= 1ull << j1;
            if (have2) { m1 = m2; j1 = j2; have2 = false; }
            else needscan = true;
        }
        if (__any(needscan)) {
            if (needscan) {
                m1 = NEG_INF; m2 = NEG_INF; j1 = 0; j2 = 0;
#pragma unroll
                for (int j = 0; j < 64; ++j) {
                    bool alive = !((remM >> j) & 1ull);
                    float vv = alive ? v[j] : NEG_INF;
                    bool c1 = vv > m1;
                    bool c2 = vv > m2;
                    m2 = c1 ? m1 : (c2 ? vv : m2);
                    j2 = c1 ? j1 : (c2 ? j : j2);
                    m1 = c1 ? vv : m1;
                    j1 = c1 ? j : j1;
                }
                have2 = true;
            }
        }
    }
}

// ---------------- top-20 from materialized pd (batch-strided) ----------------
__global__ __launch_bounds__(256) void topk20(const float* __restrict__ pd0,
                                              int* __restrict__ idxout,
                                              int bbase, size_t pdstride) {
    int b = bbase + blockIdx.y;
    const float* pd = pd0 + (size_t)blockIdx.y * pdstride;
    int row = blockIdx.x * 4 + (threadIdx.x >> 6);
    int lane = threadIdx.x & 63;
    const float4* prow4 = (const float4*)(pd + (size_t)row * NPT);
    float v[64];
#pragma unroll
    for (int q = 0; q < 16; ++q) {
        float4 t = prow4[q * 64 + lane];
        v[q * 4 + 0] = t.x; v[q * 4 + 1] = t.y;
        v[q * 4 + 2] = t.z; v[q * 4 + 3] = t.w;
    }
    topk_core(v, lane, b, idxout + (size_t)(b * NPT + row) * 20);
}

// ---------------- layer-1 (C=1) fused pd+topk: pd computed inline ----------------
__global__ __launch_bounds__(256) void topk1(const float* __restrict__ X,
                                             const float* __restrict__ xx,
                                             int* __restrict__ idxout) {
    int b = blockIdx.y;
    int row = blockIdx.x * 4 + (threadIdx.x >> 6);
    int lane = threadIdx.x & 63;
    int p0 = b * NPT;
    float xr = X[p0 + row];
    float xxr = xx[p0 + row];
    const float4* xb4 = (const float4*)(X + p0);
    const float4* xxb4 = (const float4*)(xx + p0);
    float v[64];
#pragma unroll
    for (int q = 0; q < 16; ++q) {
        float4 xm = xb4[q * 64 + lane];
        float4 xxm = xxb4[q * 64 + lane];
        v[q * 4 + 0] = (2.f * (xr * xm.x) - xxr) - xxm.x;
        v[q * 4 + 1] = (2.f * (xr * xm.y) - xxr) - xxm.y;
        v[q * 4 + 2] = (2.f * (xr * xm.z) - xxr) - xxm.z;
        v[q * 4 + 3] = (2.f * (xr * xm.w) - xxr) - xxm.w;
    }
    topk_core(v, lane, b, idxout + (size_t)(b * NPT + row) * 20);
}

// ---------------- layer-1 U/T: outer product (C=1, O=64) ----------------
__global__ __launch_bounds__(256) void ut1(const float* __restrict__ X,
                                           const float* __restrict__ w,
                                           float* __restrict__ U,
                                           float* __restrict__ T) {
    int p = blockIdx.x * 4 + (threadIdx.x >> 6);
    int o = threadIdx.x & 63;
    float xv = X[p];
    float wa = w[o * 2];
    float wt = w[o * 2 + 1] - wa;
    U[(size_t)p * 64 + o] = wa * xv;
    T[(size_t)p * 64 + o] = wt * xv;
}

// ---------------- U = wA * X, T = (wB - wA) * X  (point-major out) ----------------
__global__ __launch_bounds__(256) void ut_gemm(const float* __restrict__ X,
                                               const float* __restrict__ w,
                                               float* __restrict__ U,
                                               float* __restrict__ T,
                                               int C, int O) {
    __shared__ float Xs[KC][PAD];
    __shared__ float Wa[KC][PAD];
    __shared__ float Wt[KC][PAD];
    int tid = threadIdx.x;
    int tx = tid & 15;
    int ty = tid >> 4;
    int pbase = blockIdx.x * 64;
    int obase = blockIdx.y * 64;
    int lc = tid & 15;
    int li = tid >> 4;
    float aU[4][4] = {}, aT[4][4] = {};
    for (int c0 = 0; c0 < C; c0 += KC) {
        int c = c0 + lc;
#pragma unroll
        for (int r = 0; r < 4; ++r) {
            int i = li + r * 16;
            Xs[lc][i] = X[(size_t)(pbase + i) * C + c];
            const float* wrow = w + (size_t)(obase + i) * (2 * C);
            float wa = wrow[c];
            Wa[lc][i] = wa;
            Wt[lc][i] = wrow[C + c] - wa;
        }
        __syncthreads();
#pragma unroll
        for (int cc = 0; cc < KC; ++cc) {
            float xv[4], wav[4], wtv[4];
#pragma unroll
            for (int i = 0; i < 4; ++i) xv[i] = Xs[cc][tx * 4 + i];
#pragma unroll
            for (int j = 0; j < 4; ++j) { wav[j] = Wa[cc][ty * 4 + j]; wtv[j] = Wt[cc][ty * 4 + j]; }
#pragma unroll
            for (int j = 0; j < 4; ++j)
#pragma unroll
                for (int i = 0; i < 4; ++i) {
                    aU[j][i] = fmaf(wav[j], xv[i], aU[j][i]);
                    aT[j][i] = fmaf(wtv[j], xv[i], aT[j][i]);
                }
        }
        __syncthreads();
    }
#pragma unroll
    for (int j = 0; j < 4; ++j)
#pragma unroll
        for (int i = 0; i < 4; ++i) {
            size_t p = pbase + tx * 4 + i;
            int o = obase + ty * 4 + j;
            U[p * O + o] = aU[j][i];
            T[p * O + o] = aT[j][i];
        }
}

// ---------------- gather neighbors, max over k, BN + LeakyReLU (float4 over o) ----
__global__ __launch_bounds__(256) void gather_max4(const float* __restrict__ U,
                                                   const float* __restrict__ T,
                                                   const int* __restrict__ idx,
                                                   const float* __restrict__ g,
                                                   const float* __restrict__ bb,
                                                   const float* __restrict__ rm,
                                                   const float* __restrict__ rv,
                                                   float* __restrict__ Xout, int O) {
    int tpp = O / 4;                      // threads per point
    int ppb = 256 / tpp;                  // points per block
    int lp = threadIdx.x / tpp;
    int o4 = (threadIdx.x % tpp) * 4;
    int p = blockIdx.x * ppb + lp;
    const int* ip = idx + (size_t)p * 20;
    float4 m = {NEG_INF, NEG_INF, NEG_INF, NEG_INF};
#pragma unroll
    for (int k = 0; k < 20; ++k) {
        int j = ip[k];
        float4 u = *(const float4*)&U[(size_t)j * O + o4];
        m.x = fmaxf(m.x, u.x); m.y = fmaxf(m.y, u.y);
        m.z = fmaxf(m.z, u.z); m.w = fmaxf(m.w, u.w);
    }
    float4 t = *(const float4*)&T[(size_t)p * O + o4];
    float4 gg = *(const float4*)&g[o4];
    float4 bv = *(const float4*)&bb[o4];
    float4 rmv = *(const float4*)&rm[o4];
    float4 rvv = *(const float4*)&rv[o4];
    float4 y;
    y.x = (m.x + t.x - rmv.x) * (gg.x / sqrtf(rvv.x + EPS)) + bv.x;
    y.y = (m.y + t.y - rmv.y) * (gg.y / sqrtf(rvv.y + EPS)) + bv.y;
    y.z = (m.z + t.z - rmv.z) * (gg.z / sqrtf(rvv.z + EPS)) + bv.z;
    y.w = (m.w + t.w - rmv.w) * (gg.w / sqrtf(rvv.w + EPS)) + bv.w;
    y.x = y.x > 0.f ? y.x : 0.2f * y.x;
    y.y = y.y > 0.f ? y.y : 0.2f * y.y;
    y.z = y.z > 0.f ? y.z : 0.2f * y.z;
    y.w = y.w > 0.f ? y.w : 0.2f * y.w;
    *(float4*)&Xout[(size_t)p * O + o4] = y;
}

// ---------------- head stage 1: 128 o x 128 p tile, 8x8/thread (single buffer) ----
__global__ __launch_bounds__(256) void head_partial(const float* __restrict__ X1,
                                                    const float* __restrict__ X2,
                                                    const float* __restrict__ X3,
                                                    const float* __restrict__ X4,
                                                    const float* __restrict__ w5,
                                                    const float* __restrict__ wreg,
                                                    const float* __restrict__ g,
                                                    const float* __restrict__ bb,
                                                    const float* __restrict__ rm,
                                                    const float* __restrict__ rv,
                                                    float* __restrict__ partial) {
    __shared__ __align__(16) float Ws[KC][PADB];   // A: o rows
    __shared__ __align__(16) float Hs[KC][PADB];   // B: p cols
    __shared__ float red[16][PADB];
    int tid = threadIdx.x;
    int tx = tid & 15;          // p group
    int ty = tid >> 4;          // o group
    int o0 = blockIdx.x * 128;  // 8 o-tiles
    int p0 = blockIdx.y * 128;  // 256 p-tiles
    int sc4 = (tid & 3) * 4;
    int spt = tid >> 2;
    float acc[2][2][4][4] = {}; // [rh(o)][ch(p)][i][j]
    for (int c0 = 0; c0 < 512; c0 += KC) {
        const float* src;
        int coff, Cs;
        if (c0 < 64)       { src = X1; coff = c0;       Cs = 64; }
        else if (c0 < 128) { src = X2; coff = c0 - 64;  Cs = 64; }
        else if (c0 < 256) { src = X3; coff = c0 - 128; Cs = 128; }
        else               { src = X4; coff = c0 - 256; Cs = 256; }
#pragma unroll
        for (int h = 0; h < 2; ++h) {
            int pt = spt + h * 64;
            float4 wv = *(const float4*)&w5[(size_t)(o0 + pt) * 512 + c0 + sc4];
            float4 hv = *(const float4*)&src[(size_t)(p0 + pt) * Cs + coff + sc4];
            Ws[sc4 + 0][pt] = wv.x; Ws[sc4 + 1][pt] = wv.y;
            Ws[sc4 + 2][pt] = wv.z; Ws[sc4 + 3][pt] = wv.w;
            Hs[sc4 + 0][pt] = hv.x; Hs[sc4 + 1][pt] = hv.y;
            Hs[sc4 + 2][pt] = hv.z; Hs[sc4 + 3][pt] = hv.w;
        }
        __syncthreads();
#pragma unroll
        for (int cc = 0; cc < KC; ++cc) {
            float4 a0 = *(const float4*)&Ws[cc][ty * 4];
            float4 a1 = *(const float4*)&Ws[cc][64 + ty * 4];
            float4 b0 = *(const float4*)&Hs[cc][tx * 4];
            float4 b1 = *(const float4*)&Hs[cc][64 + tx * 4];
            float ar[2][4] = {{a0.x, a0.y, a0.z, a0.w}, {a1.x, a1.y, a1.z, a1.w}};
            float br[2][4] = {{b0.x, b0.y, b0.z, b0.w}, {b1.x, b1.y, b1.z, b1.w}};
#pragma unroll
            for (int rh = 0; rh < 2; ++rh)
#pragma unroll
                for (int i = 0; i < 4; ++i)
#pragma unroll
                    for (int ch = 0; ch < 2; ++ch)
#pragma unroll
                        for (int j = 0; j < 4; ++j)
                            acc[rh][ch][i][j] = fmaf(ar[rh][i], br[ch][j], acc[rh][ch][i][j]);
        }
        __syncthreads();
    }
    float pacc[2][4] = {};
#pragma unroll
    for (int rh = 0; rh < 2; ++rh)
#pragma unroll
        for (int i = 0; i < 4; ++i) {
            int o = o0 + rh * 64 + ty * 4 + i;
            float scale = g[o] / sqrtf(rv[o] + EPS);
            float sm = rm[o], sb = bb[o], wr = wreg[o];
#pragma unroll
            for (int ch = 0; ch < 2; ++ch)
#pragma unroll
                for (int j = 0; j < 4; ++j) {
                    float y = (acc[rh][ch][i][j] - sm) * scale + sb;
                    y = y > 0.f ? y : 0.2f * y;
                    pacc[ch][j] = fmaf(wr, y, pacc[ch][j]);
                }
        }
#pragma unroll
    for (int ch = 0; ch < 2; ++ch)
#pragma unroll
        for (int j = 0; j < 4; ++j)
            red[ty][ch * 64 + tx * 4 + j] = pacc[ch][j];
    __syncthreads();
    if (tid < 128) {
        float s = 0.f;
#pragma unroll
        for (int q = 0; q < 16; ++q) s += red[q][tid];
        partial[(size_t)blockIdx.x * PTS + p0 + tid] = s;
    }
}

// ---------------- head stage 2: out[p] = sum over 8 o-tiles ----------------
__global__ __launch_bounds__(256) void head_reduce(const float* __restrict__ partial,
                                                   float* __restrict__ out) {
    int p = blockIdx.x * 256 + threadIdx.x;
    if (p >= PTS) return;
    float s = 0.f;
#pragma unroll
    for (int q = 0; q < 8; ++q) s += partial[(size_t)q * PTS + p];
    out[p] = s;
}

extern "C" void kernel_launch(void* const* d_in, const int* in_sizes, int n_in,
                              void* d_out, int out_size, void* d_ws, size_t ws_size,
                              hipStream_t stream) {
    const float* x    = (const float*)d_in[0];
    const float* w1   = (const float*)d_in[1];
    const float* w2   = (const float*)d_in[2];
    const float* w3   = (const float*)d_in[3];
    const float* w4   = (const float*)d_in[4];
    const float* w5   = (const float*)d_in[5];
    const float* wreg = (const float*)d_in[6];
    const float* bn[5][4];
    for (int t = 0; t < 5; ++t)
        for (int q = 0; q < 4; ++q)
            bn[t][q] = (const float*)d_in[7 + t * 4 + q];
    float* out = (float*)d_out;

    // workspace layout (bytes). Base footprint ~131 MB (proven OK). If ws_size
    // also fits a SECOND 64 MB PD slab (~195 MB), process batches in pairs.
    // bf16 hi/lo planes alias the X4 slab (X4 written only by layer-4 gather,
    // after the last pd/topk consumed them).
    char* ws = (char*)d_ws;
    size_t o_x1  = 0;
    size_t o_x2  = o_x1  + (size_t)PTS * 64 * 4;
    size_t o_x3  = o_x2  + (size_t)PTS * 64 * 4;
    size_t o_x4  = o_x3  + (size_t)PTS * 128 * 4;
    size_t o_idx = o_x4  + (size_t)PTS * 256 * 4;
    size_t o_xx  = o_idx + (size_t)PTS * 20 * 4;
    size_t o_pd  = o_xx  + (size_t)PTS * 4;
    size_t o_u   = o_pd;                            // alias: U over PD slab
    size_t o_t   = o_u   + (size_t)PTS * 256 * 4;
    size_t pdslab = (size_t)NPT * NPT * 4;          // 64 MB
    (void)o_t;

    float* X1 = (float*)(ws + o_x1);
    float* X2 = (float*)(ws + o_x2);
    float* X3 = (float*)(ws + o_x3);
    float* X4 = (float*)(ws + o_x4);
    int*   IDX = (int*)(ws + o_idx);
    float* XX = (float*)(ws + o_xx);
    float* PD = (float*)(ws + o_pd);
    float* U  = (float*)(ws + o_u);
    float* T  = (float*)(ws + o_u + (size_t)PTS * 256 * 4);
    float* PART = (float*)(ws + o_idx);             // 1 MB < IDX slab
    ushort* XH = (ushort*)(ws + o_x4);              // bf16 hi plane (<=8 MB)
    ushort* XL = (ushort*)(ws + o_x4 + (size_t)PTS * 128 * 2);  // lo plane

    // pair-batching if workspace allows two PD slabs (both L3-resident)
    const bool pair = ws_size >= o_pd + 2 * pdslab;
    const int bstep = pair ? 2 : 1;
    const size_t pdstride = pair ? (size_t)NPT * NPT : 0;   // floats

    auto knn_layer = [&](int C) {
        for (int b = 0; b < BATCH; b += bstep) {
            pd_mfma<<<dim3(528, bstep), 256, 0, stream>>>(XH, XL, XX, PD, C, b, pdstride);
            topk20<<<dim3(NPT / 4, bstep), 256, 0, stream>>>(PD, IDX, b, pdstride);
        }
    };

    // ---- layer 1 (C=1 -> O=64) ----
    sqnorm<<<PTS / 256, 256, 0, stream>>>(x, XX, 1);
    topk1<<<dim3(NPT / 4, BATCH), 256, 0, stream>>>(x, XX, IDX);
    ut1<<<PTS / 4, 256, 0, stream>>>(x, w1, U, T);
    gather_max4<<<PTS * 16 / 256, 256, 0, stream>>>(U, T, IDX,
            bn[0][0], bn[0][1], bn[0][2], bn[0][3], X1, 64);

    // ---- layer 2 (C=64 -> O=64) ----
    sqnorm_cvt<<<PTS / 256, 256, 0, stream>>>(X1, XX, XH, XL, 64);
    knn_layer(64);
    ut_gemm<<<dim3(PTS / 64, 1), 256, 0, stream>>>(X1, w2, U, T, 64, 64);
    gather_max4<<<PTS * 16 / 256, 256, 0, stream>>>(U, T, IDX,
            bn[1][0], bn[1][1], bn[1][2], bn[1][3], X2, 64);

    // ---- layer 3 (C=64 -> O=128) ----
    sqnorm_cvt<<<PTS / 256, 256, 0, stream>>>(X2, XX, XH, XL, 64);
    knn_layer(64);
    ut_gemm<<<dim3(PTS / 64, 2), 256, 0, stream>>>(X2, w3, U, T, 64, 128);
    gather_max4<<<PTS * 32 / 256, 256, 0, stream>>>(U, T, IDX,
            bn[2][0], bn[2][1], bn[2][2], bn[2][3], X3, 128);

    // ---- layer 4 (C=128 -> O=256) ----
    sqnorm_cvt<<<PTS / 256, 256, 0, stream>>>(X3, XX, XH, XL, 128);
    knn_layer(128);
    ut_gemm<<<dim3(PTS / 64, 4), 256, 0, stream>>>(X3, w4, U, T, 128, 256);
    gather_max4<<<PTS * 64 / 256, 256, 0, stream>>>(U, T, IDX,
            bn[3][0], bn[3][1], bn[3][2], bn[3][3], X4, 256);

    // ---- fused head ----
    head_partial<<<dim3(8, PTS / 128), 256, 0, stream>>>(X1, X2, X3, X4, w5, wreg,
            bn[4][0], bn[4][1], bn[4][2], bn[4][3], PART);
    head_reduce<<<PTS / 256, 256, 0, stream>>>(PART, out);
}

// Round 12
// 2158.597 us; speedup vs baseline: 1.1149x; 1.1149x over previous
//
#include <hip/hip_runtime.h>
#include <math.h>

// DGCNN_Reg: B=8, N=4096, k=20.
// Point-major layouts: X[p][c], U[p][o], T[p][o] with p = b*4096 + n.
// Edge conv factorized: y[o,n,k] = U[idx[n,k]][o] + T[n][o];
// BN+LeakyReLU (scale>0) commutes with max over k.
// R12 (single change vs R11): head GEMM -> bf16x4-split MFMA (hh+hl+lh+ll).
// head is VALU-bound (75% busy, 400us vs 219us fp32 floor) unlike pd
// (store-bound, R11 neutral). w5 pre-split into hi/lo planes (w5cvt, stored
// in dead U region); H converted in-kernel during LDS staging.

constexpr int NPT = 4096;
constexpr int BATCH = 8;
constexpr int PTS = BATCH * NPT;   // 32768
constexpr float EPS = 1e-5f;
#define KC 16
#define PAD 68    // 64-wide tiles: 68 mod 32 = 4 -> conflict-free staging
#define NEG_INF -3.4e38f

typedef __attribute__((ext_vector_type(8))) short bf16x8;
typedef __attribute__((ext_vector_type(4))) float f32x4;

__device__ __forceinline__ ushort f2bf(float f) {      // RNE truncate to bf16
    unsigned u = __float_as_uint(f);
    return (ushort)((u + 0x7fffu + ((u >> 16) & 1u)) >> 16);
}
__device__ __forceinline__ unsigned pack2(ushort a, ushort b) {
    return (unsigned)a | ((unsigned)b << 16);
}

// ---------------- sum of squares per point (layer 1; xx only) ----------------
__global__ __launch_bounds__(256) void sqnorm(const float* __restrict__ X,
                                              float* __restrict__ xx, int C) {
    int p = blockIdx.x * 256 + threadIdx.x;
    if (p >= PTS) return;
    float s = 0.f;
    const float* row = X + (size_t)p * C;
    for (int c = 0; c < C; ++c) s = fmaf(row[c], row[c], s);
    xx[p] = s;
}

// ---------------- sqnorm + bf16 hi/lo split planes (layers 2-4) ----------------
__global__ __launch_bounds__(256) void sqnorm_cvt(const float* __restrict__ X,
                                                  float* __restrict__ xx,
                                                  ushort* __restrict__ Xh,
                                                  ushort* __restrict__ Xl, int C) {
    int p = blockIdx.x * 256 + threadIdx.x;
    if (p >= PTS) return;
    const float* row = X + (size_t)p * C;
    ushort* hr = Xh + (size_t)p * C;
    ushort* lr = Xl + (size_t)p * C;
    float s = 0.f;
    for (int c = 0; c < C; ++c) {
        float v = row[c];
        s = fmaf(v, v, s);
        ushort hb = f2bf(v);
        float hf = __uint_as_float((unsigned)hb << 16);
        hr[c] = hb;
        lr[c] = f2bf(v - hf);
    }
    xx[p] = s;
}

// ---------------- w5 -> bf16 hi/lo planes (once per launch) ----------------
__global__ __launch_bounds__(256) void w5cvt(const float* __restrict__ w5,
                                             ushort* __restrict__ wh,
                                             ushort* __restrict__ wl) {
    int i = blockIdx.x * 256 + threadIdx.x;     // 131072 threads x 4 elems
    int e = i * 4;
    float4 v = *(const float4*)&w5[e];
    float vv[4] = {v.x, v.y, v.z, v.w};
#pragma unroll
    for (int q = 0; q < 4; ++q) {
        ushort hb = f2bf(vv[q]);
        float hf = __uint_as_float((unsigned)hb << 16);
        wh[e + q] = hb;
        wl[e + q] = f2bf(vv[q] - hf);
    }
}

// ---------------- symmetric pd via MFMA (bf16x3), 128x128 tiles, upper tri ------
__global__ __launch_bounds__(256) void pd_mfma(const ushort* __restrict__ Xh,
                                               const ushort* __restrict__ Xl,
                                               const float* __restrict__ xx,
                                               float* __restrict__ pd0,
                                               int C, int bbase, size_t pdstride) {
    int b = bbase + blockIdx.y;
    float* pd = pd0 + (size_t)blockIdx.y * pdstride;
    int bid = blockIdx.x;
    int ti = 0, rem = bid;
    while (rem >= 32 - ti) { rem -= 32 - ti; ++ti; }
    int tj = ti + rem;
    int rowbase = ti * 128, colbase = tj * 128;
    int p0 = b * NPT;

    __shared__ ushort Rh[128][40], Rl[128][40], Ch[128][40], Cl[128][40];
    __shared__ float xxr[128], xxc[128];
    int tid = threadIdx.x;
    int lane = tid & 63, wid = tid >> 6;
    int wr = wid >> 1, wc = wid & 1;

    if (tid < 128) xxr[tid] = xx[p0 + rowbase + tid];
    else           xxc[tid - 128] = xx[p0 + colbase + tid - 128];

    const int pt = tid >> 1;            // staging point 0..127
    const int co = (tid & 1) * 16;      // staging channel base {0,16}
    size_t rrow = (size_t)(p0 + rowbase + pt) * C;
    size_t crow = (size_t)(p0 + colbase + pt) * C;

    f32x4 z = {0.f, 0.f, 0.f, 0.f};
    f32x4 acc[4][4];
#pragma unroll
    for (int sr = 0; sr < 4; ++sr)
#pragma unroll
        for (int sc = 0; sc < 4; ++sc) acc[sr][sc] = z;

    for (int c0 = 0; c0 < C; c0 += 32) {
        uint4 vrh0 = *(const uint4*)&Xh[rrow + c0 + co];
        uint4 vrh1 = *(const uint4*)&Xh[rrow + c0 + co + 8];
        uint4 vrl0 = *(const uint4*)&Xl[rrow + c0 + co];
        uint4 vrl1 = *(const uint4*)&Xl[rrow + c0 + co + 8];
        uint4 vch0 = *(const uint4*)&Xh[crow + c0 + co];
        uint4 vch1 = *(const uint4*)&Xh[crow + c0 + co + 8];
        uint4 vcl0 = *(const uint4*)&Xl[crow + c0 + co];
        uint4 vcl1 = *(const uint4*)&Xl[crow + c0 + co + 8];
        __syncthreads();                 // prior K-step's LDS reads done
        *(uint4*)&Rh[pt][co] = vrh0; *(uint4*)&Rh[pt][co + 8] = vrh1;
        *(uint4*)&Rl[pt][co] = vrl0; *(uint4*)&Rl[pt][co + 8] = vrl1;
        *(uint4*)&Ch[pt][co] = vch0; *(uint4*)&Ch[pt][co + 8] = vch1;
        *(uint4*)&Cl[pt][co] = vcl0; *(uint4*)&Cl[pt][co + 8] = vcl1;
        __syncthreads();
        bf16x8 ah[4], al[4], bh[4], bl[4];
#pragma unroll
        for (int s = 0; s < 4; ++s) {
            int ar = wr * 64 + s * 16 + (lane & 15);
            int br = wc * 64 + s * 16 + (lane & 15);
            int ko = (lane >> 4) * 8;
            ah[s] = *(const bf16x8*)&Rh[ar][ko];
            al[s] = *(const bf16x8*)&Rl[ar][ko];
            bh[s] = *(const bf16x8*)&Ch[br][ko];
            bl[s] = *(const bf16x8*)&Cl[br][ko];
        }
#pragma unroll
        for (int sr = 0; sr < 4; ++sr)
#pragma unroll
            for (int sc = 0; sc < 4; ++sc) {
                acc[sr][sc] = __builtin_amdgcn_mfma_f32_16x16x32_bf16(ah[sr], bh[sc], acc[sr][sc], 0, 0, 0);
                acc[sr][sc] = __builtin_amdgcn_mfma_f32_16x16x32_bf16(ah[sr], bl[sc], acc[sr][sc], 0, 0, 0);
                acc[sr][sc] = __builtin_amdgcn_mfma_f32_16x16x32_bf16(al[sr], bh[sc], acc[sr][sc], 0, 0, 0);
            }
    }

    int rl0 = wr * 64 + (lane >> 4) * 4;
    int ml  = wc * 64 + (lane & 15);
#pragma unroll
    for (int sr = 0; sr < 4; ++sr)
#pragma unroll
        for (int sc = 0; sc < 4; ++sc) {
            int mm = ml + sc * 16;
            float xm = xxc[mm];
#pragma unroll
            for (int reg = 0; reg < 4; ++reg) {
                int rr = rl0 + sr * 16 + reg;
                float o = 2.f * acc[sr][sc][reg] - xxr[rr] - xm;
                pd[(size_t)(rowbase + rr) * NPT + colbase + mm] = o;
            }
        }
    if (ti != tj) {
#pragma unroll
        for (int sr = 0; sr < 4; ++sr) {
            int rr0 = rl0 + sr * 16;
#pragma unroll
            for (int sc = 0; sc < 4; ++sc) {
                int mm = ml + sc * 16;
                float xm = xxc[mm];
                float4 o;
                o.x = 2.f * acc[sr][sc][0] - xm - xxr[rr0 + 0];
                o.y = 2.f * acc[sr][sc][1] - xm - xxr[rr0 + 1];
                o.z = 2.f * acc[sr][sc][2] - xm - xxr[rr0 + 2];
                o.w = 2.f * acc[sr][sc][3] - xm - xxr[rr0 + 3];
                *(float4*)&pd[(size_t)(colbase + mm) * NPT + rowbase + rr0] = o;
            }
        }
    }
}

// ---------------- shared topk core: per-lane top-2 + lazy rescan ----------------
__device__ __forceinline__ void topk_core(float (&v)[64], int lane, int b,
                                          int* __restrict__ op) {
    float m1 = NEG_INF, m2 = NEG_INF;
    int j1 = 0, j2 = 0;
#pragma unroll
    for (int j = 0; j < 64; ++j) {
        float vv = v[j];
        bool c1 = vv > m1;          // strict > : earlier (smaller) j wins ties
        bool c2 = vv > m2;
        m2 = c1 ? m1 : (c2 ? vv : m2);
        j2 = c1 ? j1 : (c2 ? j : j2);
        m1 = c1 ? vv : m1;
        j1 = c1 ? j : j1;
    }
    bool have2 = true;
    unsigned long long remM = 0ull;
    for (int t = 0; t < 20; ++t) {
        int g1 = ((j1 >> 2) << 8) + (lane << 2) + (j1 & 3);
        float bv = m1; int gi = g1;
#pragma unroll
        for (int s = 1; s < 64; s <<= 1) {
            float ov = __shfl_xor(bv, s);
            int og = __shfl_xor(gi, s);
            if (ov > bv || (ov == bv && og < gi)) { bv = ov; gi = og; }
        }
        if (lane == 0) op[t] = b * NPT + gi;
        bool needscan = false;
        if (gi == g1) {
            remM |= 1ull << j1;
            if (have2) { m1 = m2; j1 = j2; have2 = false; }
            else needscan = true;
        }
        if (__any(needscan)) {
            if (needscan) {
                m1 = NEG_INF; m2 = NEG_INF; j1 = 0; j2 = 0;
#pragma unroll
                for (int j = 0; j < 64; ++j) {
                    bool alive = !((remM >> j) & 1ull);
                    float vv = alive ? v[j] : NEG_INF;
                    bool c1 = vv > m1;
                    bool c2 = vv > m2;
                    m2 = c1 ? m1 : (c2 ? vv : m2);
                    j2 = c1 ? j1 : (c2 ? j : j2);
                    m1 = c1 ? vv : m1;
                    j1 = c1 ? j : j1;
                }
                have2 = true;
            }
        }
    }
}

// ---------------- top-20 from materialized pd (batch-strided) ----------------
__global__ __launch_bounds__(256) void topk20(const float* __restrict__ pd0,
                                              int* __restrict__ idxout,
                                              int bbase, size_t pdstride) {
    int b = bbase + blockIdx.y;
    const float* pd = pd0 + (size_t)blockIdx.y * pdstride;
    int row = blockIdx.x * 4 + (threadIdx.x >> 6);
    int lane = threadIdx.x & 63;
    const float4* prow4 = (const float4*)(pd + (size_t)row * NPT);
    float v[64];
#pragma unroll
    for (int q = 0; q < 16; ++q) {
        float4 t = prow4[q * 64 + lane];
        v[q * 4 + 0] = t.x; v[q * 4 + 1] = t.y;
        v[q * 4 + 2] = t.z; v[q * 4 + 3] = t.w;
    }
    topk_core(v, lane, b, idxout + (size_t)(b * NPT + row) * 20);
}

// ---------------- layer-1 (C=1) fused pd+topk ----------------
__global__ __launch_bounds__(256) void topk1(const float* __restrict__ X,
                                             const float* __restrict__ xx,
                                             int* __restrict__ idxout) {
    int b = blockIdx.y;
    int row = blockIdx.x * 4 + (threadIdx.x >> 6);
    int lane = threadIdx.x & 63;
    int p0 = b * NPT;
    float xr = X[p0 + row];
    float xxr = xx[p0 + row];
    const float4* xb4 = (const float4*)(X + p0);
    const float4* xxb4 = (const float4*)(xx + p0);
    float v[64];
#pragma unroll
    for (int q = 0; q < 16; ++q) {
        float4 xm = xb4[q * 64 + lane];
        float4 xxm = xxb4[q * 64 + lane];
        v[q * 4 + 0] = (2.f * (xr * xm.x) - xxr) - xxm.x;
        v[q * 4 + 1] = (2.f * (xr * xm.y) - xxr) - xxm.y;
        v[q * 4 + 2] = (2.f * (xr * xm.z) - xxr) - xxm.z;
        v[q * 4 + 3] = (2.f * (xr * xm.w) - xxr) - xxm.w;
    }
    topk_core(v, lane, b, idxout + (size_t)(b * NPT + row) * 20);
}

// ---------------- layer-1 U/T: outer product (C=1, O=64) ----------------
__global__ __launch_bounds__(256) void ut1(const float* __restrict__ X,
                                           const float* __restrict__ w,
                                           float* __restrict__ U,
                                           float* __restrict__ T) {
    int p = blockIdx.x * 4 + (threadIdx.x >> 6);
    int o = threadIdx.x & 63;
    float xv = X[p];
    float wa = w[o * 2];
    float wt = w[o * 2 + 1] - wa;
    U[(size_t)p * 64 + o] = wa * xv;
    T[(size_t)p * 64 + o] = wt * xv;
}

// ---------------- U = wA * X, T = (wB - wA) * X  (point-major out) ----------------
__global__ __launch_bounds__(256) void ut_gemm(const float* __restrict__ X,
                                               const float* __restrict__ w,
                                               float* __restrict__ U,
                                               float* __restrict__ T,
                                               int C, int O) {
    __shared__ float Xs[KC][PAD];
    __shared__ float Wa[KC][PAD];
    __shared__ float Wt[KC][PAD];
    int tid = threadIdx.x;
    int tx = tid & 15;
    int ty = tid >> 4;
    int pbase = blockIdx.x * 64;
    int obase = blockIdx.y * 64;
    int lc = tid & 15;
    int li = tid >> 4;
    float aU[4][4] = {}, aT[4][4] = {};
    for (int c0 = 0; c0 < C; c0 += KC) {
        int c = c0 + lc;
#pragma unroll
        for (int r = 0; r < 4; ++r) {
            int i = li + r * 16;
            Xs[lc][i] = X[(size_t)(pbase + i) * C + c];
            const float* wrow = w + (size_t)(obase + i) * (2 * C);
            float wa = wrow[c];
            Wa[lc][i] = wa;
            Wt[lc][i] = wrow[C + c] - wa;
        }
        __syncthreads();
#pragma unroll
        for (int cc = 0; cc < KC; ++cc) {
            float xv[4], wav[4], wtv[4];
#pragma unroll
            for (int i = 0; i < 4; ++i) xv[i] = Xs[cc][tx * 4 + i];
#pragma unroll
            for (int j = 0; j < 4; ++j) { wav[j] = Wa[cc][ty * 4 + j]; wtv[j] = Wt[cc][ty * 4 + j]; }
#pragma unroll
            for (int j = 0; j < 4; ++j)
#pragma unroll
                for (int i = 0; i < 4; ++i) {
                    aU[j][i] = fmaf(wav[j], xv[i], aU[j][i]);
                    aT[j][i] = fmaf(wtv[j], xv[i], aT[j][i]);
                }
        }
        __syncthreads();
    }
#pragma unroll
    for (int j = 0; j < 4; ++j)
#pragma unroll
        for (int i = 0; i < 4; ++i) {
            size_t p = pbase + tx * 4 + i;
            int o = obase + ty * 4 + j;
            U[p * O + o] = aU[j][i];
            T[p * O + o] = aT[j][i];
        }
}

// ---------------- gather neighbors, max over k, BN + LeakyReLU (float4 over o) ----
__global__ __launch_bounds__(256) void gather_max4(const float* __restrict__ U,
                                                   const float* __restrict__ T,
                                                   const int* __restrict__ idx,
                                                   const float* __restrict__ g,
                                                   const float* __restrict__ bb,
                                                   const float* __restrict__ rm,
                                                   const float* __restrict__ rv,
                                                   float* __restrict__ Xout, int O) {
    int tpp = O / 4;
    int ppb = 256 / tpp;
    int lp = threadIdx.x / tpp;
    int o4 = (threadIdx.x % tpp) * 4;
    int p = blockIdx.x * ppb + lp;
    const int* ip = idx + (size_t)p * 20;
    float4 m = {NEG_INF, NEG_INF, NEG_INF, NEG_INF};
#pragma unroll
    for (int k = 0; k < 20; ++k) {
        int j = ip[k];
        float4 u = *(const float4*)&U[(size_t)j * O + o4];
        m.x = fmaxf(m.x, u.x); m.y = fmaxf(m.y, u.y);
        m.z = fmaxf(m.z, u.z); m.w = fmaxf(m.w, u.w);
    }
    float4 t = *(const float4*)&T[(size_t)p * O + o4];
    float4 gg = *(const float4*)&g[o4];
    float4 bv = *(const float4*)&bb[o4];
    float4 rmv = *(const float4*)&rm[o4];
    float4 rvv = *(const float4*)&rv[o4];
    float4 y;
    y.x = (m.x + t.x - rmv.x) * (gg.x / sqrtf(rvv.x + EPS)) + bv.x;
    y.y = (m.y + t.y - rmv.y) * (gg.y / sqrtf(rvv.y + EPS)) + bv.y;
    y.z = (m.z + t.z - rmv.z) * (gg.z / sqrtf(rvv.z + EPS)) + bv.z;
    y.w = (m.w + t.w - rmv.w) * (gg.w / sqrtf(rvv.w + EPS)) + bv.w;
    y.x = y.x > 0.f ? y.x : 0.2f * y.x;
    y.y = y.y > 0.f ? y.y : 0.2f * y.y;
    y.z = y.z > 0.f ? y.z : 0.2f * y.z;
    y.w = y.w > 0.f ? y.w : 0.2f * y.w;
    *(float4*)&Xout[(size_t)p * O + o4] = y;
}

// ---------------- head via MFMA: 128o x 128p tiles, bf16x4 split ----------------
// 4 waves, 64x64 quadrants (wr = o dir, wc = p dir). W from precomputed planes;
// H converted fp32->hi/lo in-kernel during staging. Epilogue: BN+lrelu+wreg dot
// in-register, shfl+LDS reduce over o.
__global__ __launch_bounds__(256) void head_mfma(const float* __restrict__ X1,
                                                 const float* __restrict__ X2,
                                                 const float* __restrict__ X3,
                                                 const float* __restrict__ X4,
                                                 const ushort* __restrict__ w5h,
                                                 const ushort* __restrict__ w5l,
                                                 const float* __restrict__ wreg,
                                                 const float* __restrict__ g,
                                                 const float* __restrict__ bb,
                                                 const float* __restrict__ rm,
                                                 const float* __restrict__ rv,
                                                 float* __restrict__ partial) {
    __shared__ ushort Hh[128][40], Hl[128][40], Wh[128][40], Wl[128][40];
    __shared__ float sscale[128], srm[128], sbb[128], swreg[128];
    __shared__ float red[2][128];
    int tid = threadIdx.x;
    int lane = tid & 63, wid = tid >> 6;
    int wr = wid >> 1, wc = wid & 1;
    int o0 = blockIdx.x * 128;
    int p0 = blockIdx.y * 128;

    if (tid < 128) {
        int o = o0 + tid;
        sscale[tid] = g[o] / sqrtf(rv[o] + EPS);
        srm[tid] = rm[o]; sbb[tid] = bb[o]; swreg[tid] = wreg[o];
    }

    const int pt = tid >> 1;            // 0..127
    const int co = (tid & 1) * 16;      // {0,16}

    f32x4 z = {0.f, 0.f, 0.f, 0.f};
    f32x4 acc[4][4];
#pragma unroll
    for (int sr = 0; sr < 4; ++sr)
#pragma unroll
        for (int sc = 0; sc < 4; ++sc) acc[sr][sc] = z;

    for (int c0 = 0; c0 < 512; c0 += 32) {
        const float* src;
        int coff, Cs;
        if (c0 < 64)       { src = X1; coff = c0;       Cs = 64; }
        else if (c0 < 128) { src = X2; coff = c0 - 64;  Cs = 64; }
        else if (c0 < 256) { src = X3; coff = c0 - 128; Cs = 128; }
        else               { src = X4; coff = c0 - 256; Cs = 256; }
        const float* hp = &src[(size_t)(p0 + pt) * Cs + coff + co];
        float4 f0 = *(const float4*)&hp[0];
        float4 f1 = *(const float4*)&hp[4];
        float4 f2 = *(const float4*)&hp[8];
        float4 f3 = *(const float4*)&hp[12];
        size_t wrow = (size_t)(o0 + pt) * 512 + c0 + co;
        uint4 wh0 = *(const uint4*)&w5h[wrow];
        uint4 wh1 = *(const uint4*)&w5h[wrow + 8];
        uint4 wl0 = *(const uint4*)&w5l[wrow];
        uint4 wl1 = *(const uint4*)&w5l[wrow + 8];
        // convert 16 H floats -> hi/lo
        float hv[16] = {f0.x, f0.y, f0.z, f0.w, f1.x, f1.y, f1.z, f1.w,
                        f2.x, f2.y, f2.z, f2.w, f3.x, f3.y, f3.z, f3.w};
        ushort hb[16], lb[16];
#pragma unroll
        for (int q = 0; q < 16; ++q) {
            hb[q] = f2bf(hv[q]);
            float hf = __uint_as_float((unsigned)hb[q] << 16);
            lb[q] = f2bf(hv[q] - hf);
        }
        uint4 hh0 = {pack2(hb[0], hb[1]), pack2(hb[2], hb[3]), pack2(hb[4], hb[5]), pack2(hb[6], hb[7])};
        uint4 hh1 = {pack2(hb[8], hb[9]), pack2(hb[10], hb[11]), pack2(hb[12], hb[13]), pack2(hb[14], hb[15])};
        uint4 hl0 = {pack2(lb[0], lb[1]), pack2(lb[2], lb[3]), pack2(lb[4], lb[5]), pack2(lb[6], lb[7])};
        uint4 hl1 = {pack2(lb[8], lb[9]), pack2(lb[10], lb[11]), pack2(lb[12], lb[13]), pack2(lb[14], lb[15])};
        __syncthreads();                 // prior K-step's frag reads done
        *(uint4*)&Hh[pt][co] = hh0; *(uint4*)&Hh[pt][co + 8] = hh1;
        *(uint4*)&Hl[pt][co] = hl0; *(uint4*)&Hl[pt][co + 8] = hl1;
        *(uint4*)&Wh[pt][co] = wh0; *(uint4*)&Wh[pt][co + 8] = wh1;
        *(uint4*)&Wl[pt][co] = wl0; *(uint4*)&Wl[pt][co + 8] = wl1;
        __syncthreads();
        bf16x8 ah[4], al[4], bh[4], bl[4];
#pragma unroll
        for (int s = 0; s < 4; ++s) {
            int orow = wr * 64 + s * 16 + (lane & 15);
            int prow = wc * 64 + s * 16 + (lane & 15);
            int ko = (lane >> 4) * 8;
            ah[s] = *(const bf16x8*)&Wh[orow][ko];
            al[s] = *(const bf16x8*)&Wl[orow][ko];
            bh[s] = *(const bf16x8*)&Hh[prow][ko];
            bl[s] = *(const bf16x8*)&Hl[prow][ko];
        }
#pragma unroll
        for (int sr = 0; sr < 4; ++sr)
#pragma unroll
            for (int sc = 0; sc < 4; ++sc) {
                acc[sr][sc] = __builtin_amdgcn_mfma_f32_16x16x32_bf16(ah[sr], bh[sc], acc[sr][sc], 0, 0, 0);
                acc[sr][sc] = __builtin_amdgcn_mfma_f32_16x16x32_bf16(ah[sr], bl[sc], acc[sr][sc], 0, 0, 0);
                acc[sr][sc] = __builtin_amdgcn_mfma_f32_16x16x32_bf16(al[sr], bh[sc], acc[sr][sc], 0, 0, 0);
                acc[sr][sc] = __builtin_amdgcn_mfma_f32_16x16x32_bf16(al[sr], bl[sc], acc[sr][sc], 0, 0, 0);
            }
    }

    // epilogue: BN + lrelu + wreg dot over this lane's 16 o-rows, per p col
    float psum[4] = {0.f, 0.f, 0.f, 0.f};     // per sc
#pragma unroll
    for (int sr = 0; sr < 4; ++sr)
#pragma unroll
        for (int reg = 0; reg < 4; ++reg) {
            int ol = wr * 64 + sr * 16 + (lane >> 4) * 4 + reg;
            float scale = sscale[ol], smv = srm[ol], sbv = sbb[ol], wrv = swreg[ol];
#pragma unroll
            for (int sc = 0; sc < 4; ++sc) {
                float y = (acc[sr][sc][reg] - smv) * scale + sbv;
                y = y > 0.f ? y : 0.2f * y;
                psum[sc] = fmaf(wrv, y, psum[sc]);
            }
        }
#pragma unroll
    for (int sc = 0; sc < 4; ++sc) {
        psum[sc] += __shfl_xor(psum[sc], 16);
        psum[sc] += __shfl_xor(psum[sc], 32);
    }
    if ((lane >> 4) == 0) {
#pragma unroll
        for (int sc = 0; sc < 4; ++sc)
            red[wr][wc * 64 + sc * 16 + lane] = psum[sc];
    }
    __syncthreads();
    if (tid < 128)
        partial[(size_t)blockIdx.x * PTS + p0 + tid] = red[0][tid] + red[1][tid];
}

// ---------------- head stage 2: out[p] = sum over 8 o-tiles ----------------
__global__ __launch_bounds__(256) void head_reduce(const float* __restrict__ partial,
                                                   float* __restrict__ out) {
    int p = blockIdx.x * 256 + threadIdx.x;
    if (p >= PTS) return;
    float s = 0.f;
#pragma unroll
    for (int q = 0; q < 8; ++q) s += partial[(size_t)q * PTS + p];
    out[p] = s;
}

extern "C" void kernel_launch(void* const* d_in, const int* in_sizes, int n_in,
                              void* d_out, int out_size, void* d_ws, size_t ws_size,
                              hipStream_t stream) {
    const float* x    = (const float*)d_in[0];
    const float* w1   = (const float*)d_in[1];
    const float* w2   = (const float*)d_in[2];
    const float* w3   = (const float*)d_in[3];
    const float* w4   = (const float*)d_in[4];
    const float* w5   = (const float*)d_in[5];
    const float* wreg = (const float*)d_in[6];
    const float* bn[5][4];
    for (int t = 0; t < 5; ++t)
        for (int q = 0; q < 4; ++q)
            bn[t][q] = (const float*)d_in[7 + t * 4 + q];
    float* out = (float*)d_out;

    // workspace layout (bytes), peak 195 MB (proven OK in pair mode).
    // bf16 X hi/lo planes alias X4 slab; w5 hi/lo planes alias U (dead at head).
    char* ws = (char*)d_ws;
    size_t o_x1  = 0;
    size_t o_x2  = o_x1  + (size_t)PTS * 64 * 4;
    size_t o_x3  = o_x2  + (size_t)PTS * 64 * 4;
    size_t o_x4  = o_x3  + (size_t)PTS * 128 * 4;
    size_t o_idx = o_x4  + (size_t)PTS * 256 * 4;
    size_t o_xx  = o_idx + (size_t)PTS * 20 * 4;
    size_t o_pd  = o_xx  + (size_t)PTS * 4;
    size_t o_u   = o_pd;                            // alias: U over PD slab
    size_t pdslab = (size_t)NPT * NPT * 4;          // 64 MB

    float* X1 = (float*)(ws + o_x1);
    float* X2 = (float*)(ws + o_x2);
    float* X3 = (float*)(ws + o_x3);
    float* X4 = (float*)(ws + o_x4);
    int*   IDX = (int*)(ws + o_idx);
    float* XX = (float*)(ws + o_xx);
    float* PD = (float*)(ws + o_pd);
    float* U  = (float*)(ws + o_u);
    float* T  = (float*)(ws + o_u + (size_t)PTS * 256 * 4);
    float* PART = (float*)(ws + o_idx);             // 1 MB < IDX slab
    ushort* XH = (ushort*)(ws + o_x4);              // bf16 hi plane (<=8 MB)
    ushort* XL = (ushort*)(ws + o_x4 + (size_t)PTS * 128 * 2);  // lo plane
    ushort* W5H = (ushort*)(ws + o_u);              // w5 planes alias U (dead at head)
    ushort* W5L = W5H + (size_t)1024 * 512;

    const bool pair = ws_size >= o_pd + 2 * pdslab;
    const int bstep = pair ? 2 : 1;
    const size_t pdstride = pair ? (size_t)NPT * NPT : 0;   // floats

    auto knn_layer = [&](int C) {
        for (int b = 0; b < BATCH; b += bstep) {
            pd_mfma<<<dim3(528, bstep), 256, 0, stream>>>(XH, XL, XX, PD, C, b, pdstride);
            topk20<<<dim3(NPT / 4, bstep), 256, 0, stream>>>(PD, IDX, b, pdstride);
        }
    };

    // ---- layer 1 (C=1 -> O=64) ----
    sqnorm<<<PTS / 256, 256, 0, stream>>>(x, XX, 1);
    topk1<<<dim3(NPT / 4, BATCH), 256, 0, stream>>>(x, XX, IDX);
    ut1<<<PTS / 4, 256, 0, stream>>>(x, w1, U, T);
    gather_max4<<<PTS * 16 / 256, 256, 0, stream>>>(U, T, IDX,
            bn[0][0], bn[0][1], bn[0][2], bn[0][3], X1, 64);

    // ---- layer 2 (C=64 -> O=64) ----
    sqnorm_cvt<<<PTS / 256, 256, 0, stream>>>(X1, XX, XH, XL, 64);
    knn_layer(64);
    ut_gemm<<<dim3(PTS / 64, 1), 256, 0, stream>>>(X1, w2, U, T, 64, 64);
    gather_max4<<<PTS * 16 / 256, 256, 0, stream>>>(U, T, IDX,
            bn[1][0], bn[1][1], bn[1][2], bn[1][3], X2, 64);

    // ---- layer 3 (C=64 -> O=128) ----
    sqnorm_cvt<<<PTS / 256, 256, 0, stream>>>(X2, XX, XH, XL, 64);
    knn_layer(64);
    ut_gemm<<<dim3(PTS / 64, 2), 256, 0, stream>>>(X2, w3, U, T, 64, 128);
    gather_max4<<<PTS * 32 / 256, 256, 0, stream>>>(U, T, IDX,
            bn[2][0], bn[2][1], bn[2][2], bn[2][3], X3, 128);

    // ---- layer 4 (C=128 -> O=256) ----
    sqnorm_cvt<<<PTS / 256, 256, 0, stream>>>(X3, XX, XH, XL, 128);
    knn_layer(128);
    ut_gemm<<<dim3(PTS / 64, 4), 256, 0, stream>>>(X3, w4, U, T, 128, 256);
    gather_max4<<<PTS * 64 / 256, 256, 0, stream>>>(U, T, IDX,
            bn[3][0], bn[3][1], bn[3][2], bn[3][3], X4, 256);

    // ---- fused head (MFMA) ----
    w5cvt<<<512, 256, 0, stream>>>(w5, W5H, W5L);
    head_mfma<<<dim3(8, PTS / 128), 256, 0, stream>>>(X1, X2, X3, X4, W5H, W5L,
            wreg, bn[4][0], bn[4][1], bn[4][2], bn[4][3], PART);
    head_reduce<<<PTS / 256, 256, 0, stream>>>(PART, out);
}

// Round 15
// 2151.531 us; speedup vs baseline: 1.1186x; 1.0033x over previous
//
#include <hip/hip_runtime.h>
#include <math.h>

// DGCNN_Reg: B=8, N=4096, k=20.
// Point-major layouts: X[p][c], U[p][o], T[p][o] with p = b*4096 + n.
// Edge conv factorized: y[o,n,k] = U[idx[n,k]][o] + T[n][o];
// BN+LeakyReLU (scale>0) commutes with max over k.
// R15: FULL REVERT to R12 (last passing, call-stable state: 2159us,
// absmax 0.015625). R13/R14's top-3 topk queue failed validation twice with
// un-attributable call-to-call variation -- reverted per discipline.
// Pipeline: topk1 fused layer-1 knn; pd via bf16x3 MFMA (symmetric, pair-
// batched); topk top-2 lazy rescan; ut factorized GEMM; gather fused BN/lrelu;
// head via bf16x4 MFMA + reduce.

constexpr int NPT = 4096;
constexpr int BATCH = 8;
constexpr int PTS = BATCH * NPT;   // 32768
constexpr float EPS = 1e-5f;
#define KC 16
#define PAD 68    // 64-wide tiles: 68 mod 32 = 4 -> conflict-free staging
#define NEG_INF -3.4e38f

typedef __attribute__((ext_vector_type(8))) short bf16x8;
typedef __attribute__((ext_vector_type(4))) float f32x4;

__device__ __forceinline__ ushort f2bf(float f) {      // RNE truncate to bf16
    unsigned u = __float_as_uint(f);
    return (ushort)((u + 0x7fffu + ((u >> 16) & 1u)) >> 16);
}
__device__ __forceinline__ unsigned pack2(ushort a, ushort b) {
    return (unsigned)a | ((unsigned)b << 16);
}

// ---------------- sum of squares per point (layer 1; xx only) ----------------
__global__ __launch_bounds__(256) void sqnorm(const float* __restrict__ X,
                                              float* __restrict__ xx, int C) {
    int p = blockIdx.x * 256 + threadIdx.x;
    if (p >= PTS) return;
    float s = 0.f;
    const float* row = X + (size_t)p * C;
    for (int c = 0; c < C; ++c) s = fmaf(row[c], row[c], s);
    xx[p] = s;
}

// ---------------- sqnorm + bf16 hi/lo split planes (layers 2-4) ----------------
__global__ __launch_bounds__(256) void sqnorm_cvt(const float* __restrict__ X,
                                                  float* __restrict__ xx,
                                                  ushort* __restrict__ Xh,
                                                  ushort* __restrict__ Xl, int C) {
    int p = blockIdx.x * 256 + threadIdx.x;
    if (p >= PTS) return;
    const float* row = X + (size_t)p * C;
    ushort* hr = Xh + (size_t)p * C;
    ushort* lr = Xl + (size_t)p * C;
    float s = 0.f;
    for (int c = 0; c < C; ++c) {
        float v = row[c];
        s = fmaf(v, v, s);
        ushort hb = f2bf(v);
        float hf = __uint_as_float((unsigned)hb << 16);
        hr[c] = hb;
        lr[c] = f2bf(v - hf);
    }
    xx[p] = s;
}

// ---------------- w5 -> bf16 hi/lo planes (once per launch) ----------------
__global__ __launch_bounds__(256) void w5cvt(const float* __restrict__ w5,
                                             ushort* __restrict__ wh,
                                             ushort* __restrict__ wl) {
    int i = blockIdx.x * 256 + threadIdx.x;     // 131072 threads x 4 elems
    int e = i * 4;
    float4 v = *(const float4*)&w5[e];
    float vv[4] = {v.x, v.y, v.z, v.w};
#pragma unroll
    for (int q = 0; q < 4; ++q) {
        ushort hb = f2bf(vv[q]);
        float hf = __uint_as_float((unsigned)hb << 16);
        wh[e + q] = hb;
        wl[e + q] = f2bf(vv[q] - hf);
    }
}

// ---------------- symmetric pd via MFMA (bf16x3), 128x128 tiles, upper tri ------
__global__ __launch_bounds__(256) void pd_mfma(const ushort* __restrict__ Xh,
                                               const ushort* __restrict__ Xl,
                                               const float* __restrict__ xx,
                                               float* __restrict__ pd0,
                                               int C, int bbase, size_t pdstride) {
    int b = bbase + blockIdx.y;
    float* pd = pd0 + (size_t)blockIdx.y * pdstride;
    int bid = blockIdx.x;
    int ti = 0, rem = bid;
    while (rem >= 32 - ti) { rem -= 32 - ti; ++ti; }
    int tj = ti + rem;
    int rowbase = ti * 128, colbase = tj * 128;
    int p0 = b * NPT;

    __shared__ ushort Rh[128][40], Rl[128][40], Ch[128][40], Cl[128][40];
    __shared__ float xxr[128], xxc[128];
    int tid = threadIdx.x;
    int lane = tid & 63, wid = tid >> 6;
    int wr = wid >> 1, wc = wid & 1;

    if (tid < 128) xxr[tid] = xx[p0 + rowbase + tid];
    else           xxc[tid - 128] = xx[p0 + colbase + tid - 128];

    const int pt = tid >> 1;            // staging point 0..127
    const int co = (tid & 1) * 16;      // staging channel base {0,16}
    size_t rrow = (size_t)(p0 + rowbase + pt) * C;
    size_t crow = (size_t)(p0 + colbase + pt) * C;

    f32x4 z = {0.f, 0.f, 0.f, 0.f};
    f32x4 acc[4][4];
#pragma unroll
    for (int sr = 0; sr < 4; ++sr)
#pragma unroll
        for (int sc = 0; sc < 4; ++sc) acc[sr][sc] = z;

    for (int c0 = 0; c0 < C; c0 += 32) {
        uint4 vrh0 = *(const uint4*)&Xh[rrow + c0 + co];
        uint4 vrh1 = *(const uint4*)&Xh[rrow + c0 + co + 8];
        uint4 vrl0 = *(const uint4*)&Xl[rrow + c0 + co];
        uint4 vrl1 = *(const uint4*)&Xl[rrow + c0 + co + 8];
        uint4 vch0 = *(const uint4*)&Xh[crow + c0 + co];
        uint4 vch1 = *(const uint4*)&Xh[crow + c0 + co + 8];
        uint4 vcl0 = *(const uint4*)&Xl[crow + c0 + co];
        uint4 vcl1 = *(const uint4*)&Xl[crow + c0 + co + 8];
        __syncthreads();                 // prior K-step's LDS reads done
        *(uint4*)&Rh[pt][co] = vrh0; *(uint4*)&Rh[pt][co + 8] = vrh1;
        *(uint4*)&Rl[pt][co] = vrl0; *(uint4*)&Rl[pt][co + 8] = vrl1;
        *(uint4*)&Ch[pt][co] = vch0; *(uint4*)&Ch[pt][co + 8] = vch1;
        *(uint4*)&Cl[pt][co] = vcl0; *(uint4*)&Cl[pt][co + 8] = vcl1;
        __syncthreads();
        bf16x8 ah[4], al[4], bh[4], bl[4];
#pragma unroll
        for (int s = 0; s < 4; ++s) {
            int ar = wr * 64 + s * 16 + (lane & 15);
            int br = wc * 64 + s * 16 + (lane & 15);
            int ko = (lane >> 4) * 8;
            ah[s] = *(const bf16x8*)&Rh[ar][ko];
            al[s] = *(const bf16x8*)&Rl[ar][ko];
            bh[s] = *(const bf16x8*)&Ch[br][ko];
            bl[s] = *(const bf16x8*)&Cl[br][ko];
        }
#pragma unroll
        for (int sr = 0; sr < 4; ++sr)
#pragma unroll
            for (int sc = 0; sc < 4; ++sc) {
                acc[sr][sc] = __builtin_amdgcn_mfma_f32_16x16x32_bf16(ah[sr], bh[sc], acc[sr][sc], 0, 0, 0);
                acc[sr][sc] = __builtin_amdgcn_mfma_f32_16x16x32_bf16(ah[sr], bl[sc], acc[sr][sc], 0, 0, 0);
                acc[sr][sc] = __builtin_amdgcn_mfma_f32_16x16x32_bf16(al[sr], bh[sc], acc[sr][sc], 0, 0, 0);
            }
    }

    int rl0 = wr * 64 + (lane >> 4) * 4;
    int ml  = wc * 64 + (lane & 15);
#pragma unroll
    for (int sr = 0; sr < 4; ++sr)
#pragma unroll
        for (int sc = 0; sc < 4; ++sc) {
            int mm = ml + sc * 16;
            float xm = xxc[mm];
#pragma unroll
            for (int reg = 0; reg < 4; ++reg) {
                int rr = rl0 + sr * 16 + reg;
                float o = 2.f * acc[sr][sc][reg] - xxr[rr] - xm;
                pd[(size_t)(rowbase + rr) * NPT + colbase + mm] = o;
            }
        }
    if (ti != tj) {
#pragma unroll
        for (int sr = 0; sr < 4; ++sr) {
            int rr0 = rl0 + sr * 16;
#pragma unroll
            for (int sc = 0; sc < 4; ++sc) {
                int mm = ml + sc * 16;
                float xm = xxc[mm];
                float4 o;
                o.x = 2.f * acc[sr][sc][0] - xm - xxr[rr0 + 0];
                o.y = 2.f * acc[sr][sc][1] - xm - xxr[rr0 + 1];
                o.z = 2.f * acc[sr][sc][2] - xm - xxr[rr0 + 2];
                o.w = 2.f * acc[sr][sc][3] - xm - xxr[rr0 + 3];
                *(float4*)&pd[(size_t)(colbase + mm) * NPT + rowbase + rr0] = o;
            }
        }
    }
}

// ---------------- shared topk core: per-lane top-2 + lazy rescan (R12 form) ------
// v[64] per lane; global col of v[j] = (j>>2)*256 + lane*4 + (j&3).
__device__ __forceinline__ void topk_core(float (&v)[64], int lane, int b,
                                          int* __restrict__ op) {
    float m1 = NEG_INF, m2 = NEG_INF;
    int j1 = 0, j2 = 0;
#pragma unroll
    for (int j = 0; j < 64; ++j) {
        float vv = v[j];
        bool c1 = vv > m1;          // strict > : earlier (smaller) j wins ties
        bool c2 = vv > m2;
        m2 = c1 ? m1 : (c2 ? vv : m2);
        j2 = c1 ? j1 : (c2 ? j : j2);
        m1 = c1 ? vv : m1;
        j1 = c1 ? j : j1;
    }
    bool have2 = true;
    unsigned long long remM = 0ull;
    for (int t = 0; t < 20; ++t) {
        int g1 = ((j1 >> 2) << 8) + (lane << 2) + (j1 & 3);
        float bv = m1; int gi = g1;
#pragma unroll
        for (int s = 1; s < 64; s <<= 1) {
            float ov = __shfl_xor(bv, s);
            int og = __shfl_xor(gi, s);
            if (ov > bv || (ov == bv && og < gi)) { bv = ov; gi = og; }
        }
        if (lane == 0) op[t] = b * NPT + gi;
        bool needscan = false;
        if (gi == g1) {             // g1 encodes lane -> unique; this lane won
            remM |= 1ull << j1;
            if (have2) { m1 = m2; j1 = j2; have2 = false; }
            else needscan = true;
        }
        if (__any(needscan)) {
            if (needscan) {
                m1 = NEG_INF; m2 = NEG_INF; j1 = 0; j2 = 0;
#pragma unroll
                for (int j = 0; j < 64; ++j) {
                    bool alive = !((remM >> j) & 1ull);
                    float vv = alive ? v[j] : NEG_INF;
                    bool c1 = vv > m1;
                    bool c2 = vv > m2;
                    m2 = c1 ? m1 : (c2 ? vv : m2);
                    j2 = c1 ? j1 : (c2 ? j : j2);
                    m1 = c1 ? vv : m1;
                    j1 = c1 ? j : j1;
                }
                have2 = true;
            }
        }
    }
}

// ---------------- top-20 from materialized pd (batch-strided) ----------------
__global__ __launch_bounds__(256) void topk20(const float* __restrict__ pd0,
                                              int* __restrict__ idxout,
                                              int bbase, size_t pdstride) {
    int b = bbase + blockIdx.y;
    const float* pd = pd0 + (size_t)blockIdx.y * pdstride;
    int row = blockIdx.x * 4 + (threadIdx.x >> 6);
    int lane = threadIdx.x & 63;
    const float4* prow4 = (const float4*)(pd + (size_t)row * NPT);
    float v[64];
#pragma unroll
    for (int q = 0; q < 16; ++q) {
        float4 t = prow4[q * 64 + lane];
        v[q * 4 + 0] = t.x; v[q * 4 + 1] = t.y;
        v[q * 4 + 2] = t.z; v[q * 4 + 3] = t.w;
    }
    topk_core(v, lane, b, idxout + (size_t)(b * NPT + row) * 20);
}

// ---------------- layer-1 (C=1) fused pd+topk ----------------
__global__ __launch_bounds__(256) void topk1(const float* __restrict__ X,
                                             const float* __restrict__ xx,
                                             int* __restrict__ idxout) {
    int b = blockIdx.y;
    int row = blockIdx.x * 4 + (threadIdx.x >> 6);
    int lane = threadIdx.x & 63;
    int p0 = b * NPT;
    float xr = X[p0 + row];
    float xxr = xx[p0 + row];
    const float4* xb4 = (const float4*)(X + p0);
    const float4* xxb4 = (const float4*)(xx + p0);
    float v[64];
#pragma unroll
    for (int q = 0; q < 16; ++q) {
        float4 xm = xb4[q * 64 + lane];
        float4 xxm = xxb4[q * 64 + lane];
        v[q * 4 + 0] = (2.f * (xr * xm.x) - xxr) - xxm.x;
        v[q * 4 + 1] = (2.f * (xr * xm.y) - xxr) - xxm.y;
        v[q * 4 + 2] = (2.f * (xr * xm.z) - xxr) - xxm.z;
        v[q * 4 + 3] = (2.f * (xr * xm.w) - xxr) - xxm.w;
    }
    topk_core(v, lane, b, idxout + (size_t)(b * NPT + row) * 20);
}

// ---------------- layer-1 U/T: outer product (C=1, O=64) ----------------
__global__ __launch_bounds__(256) void ut1(const float* __restrict__ X,
                                           const float* __restrict__ w,
                                           float* __restrict__ U,
                                           float* __restrict__ T) {
    int p = blockIdx.x * 4 + (threadIdx.x >> 6);
    int o = threadIdx.x & 63;
    float xv = X[p];
    float wa = w[o * 2];
    float wt = w[o * 2 + 1] - wa;
    U[(size_t)p * 64 + o] = wa * xv;
    T[(size_t)p * 64 + o] = wt * xv;
}

// ---------------- U = wA * X, T = (wB - wA) * X  (point-major out) ----------------
__global__ __launch_bounds__(256) void ut_gemm(const float* __restrict__ X,
                                               const float* __restrict__ w,
                                               float* __restrict__ U,
                                               float* __restrict__ T,
                                               int C, int O) {
    __shared__ float Xs[KC][PAD];
    __shared__ float Wa[KC][PAD];
    __shared__ float Wt[KC][PAD];
    int tid = threadIdx.x;
    int tx = tid & 15;
    int ty = tid >> 4;
    int pbase = blockIdx.x * 64;
    int obase = blockIdx.y * 64;
    int lc = tid & 15;
    int li = tid >> 4;
    float aU[4][4] = {}, aT[4][4] = {};
    for (int c0 = 0; c0 < C; c0 += KC) {
        int c = c0 + lc;
#pragma unroll
        for (int r = 0; r < 4; ++r) {
            int i = li + r * 16;
            Xs[lc][i] = X[(size_t)(pbase + i) * C + c];
            const float* wrow = w + (size_t)(obase + i) * (2 * C);
            float wa = wrow[c];
            Wa[lc][i] = wa;
            Wt[lc][i] = wrow[C + c] - wa;
        }
        __syncthreads();
#pragma unroll
        for (int cc = 0; cc < KC; ++cc) {
            float xv[4], wav[4], wtv[4];
#pragma unroll
            for (int i = 0; i < 4; ++i) xv[i] = Xs[cc][tx * 4 + i];
#pragma unroll
            for (int j = 0; j < 4; ++j) { wav[j] = Wa[cc][ty * 4 + j]; wtv[j] = Wt[cc][ty * 4 + j]; }
#pragma unroll
            for (int j = 0; j < 4; ++j)
#pragma unroll
                for (int i = 0; i < 4; ++i) {
                    aU[j][i] = fmaf(wav[j], xv[i], aU[j][i]);
                    aT[j][i] = fmaf(wtv[j], xv[i], aT[j][i]);
                }
        }
        __syncthreads();
    }
#pragma unroll
    for (int j = 0; j < 4; ++j)
#pragma unroll
        for (int i = 0; i < 4; ++i) {
            size_t p = pbase + tx * 4 + i;
            int o = obase + ty * 4 + j;
            U[p * O + o] = aU[j][i];
            T[p * O + o] = aT[j][i];
        }
}

// ---------------- gather neighbors, max over k, BN + LeakyReLU (float4 over o) ----
__global__ __launch_bounds__(256) void gather_max4(const float* __restrict__ U,
                                                   const float* __restrict__ T,
                                                   const int* __restrict__ idx,
                                                   const float* __restrict__ g,
                                                   const float* __restrict__ bb,
                                                   const float* __restrict__ rm,
                                                   const float* __restrict__ rv,
                                                   float* __restrict__ Xout, int O) {
    int tpp = O / 4;
    int ppb = 256 / tpp;
    int lp = threadIdx.x / tpp;
    int o4 = (threadIdx.x % tpp) * 4;
    int p = blockIdx.x * ppb + lp;
    const int* ip = idx + (size_t)p * 20;
    float4 m = {NEG_INF, NEG_INF, NEG_INF, NEG_INF};
#pragma unroll
    for (int k = 0; k < 20; ++k) {
        int j = ip[k];
        float4 u = *(const float4*)&U[(size_t)j * O + o4];
        m.x = fmaxf(m.x, u.x); m.y = fmaxf(m.y, u.y);
        m.z = fmaxf(m.z, u.z); m.w = fmaxf(m.w, u.w);
    }
    float4 t = *(const float4*)&T[(size_t)p * O + o4];
    float4 gg = *(const float4*)&g[o4];
    float4 bv = *(const float4*)&bb[o4];
    float4 rmv = *(const float4*)&rm[o4];
    float4 rvv = *(const float4*)&rv[o4];
    float4 y;
    y.x = (m.x + t.x - rmv.x) * (gg.x / sqrtf(rvv.x + EPS)) + bv.x;
    y.y = (m.y + t.y - rmv.y) * (gg.y / sqrtf(rvv.y + EPS)) + bv.y;
    y.z = (m.z + t.z - rmv.z) * (gg.z / sqrtf(rvv.z + EPS)) + bv.z;
    y.w = (m.w + t.w - rmv.w) * (gg.w / sqrtf(rvv.w + EPS)) + bv.w;
    y.x = y.x > 0.f ? y.x : 0.2f * y.x;
    y.y = y.y > 0.f ? y.y : 0.2f * y.y;
    y.z = y.z > 0.f ? y.z : 0.2f * y.z;
    y.w = y.w > 0.f ? y.w : 0.2f * y.w;
    *(float4*)&Xout[(size_t)p * O + o4] = y;
}

// ---------------- head via MFMA: 128o x 128p tiles, bf16x4 split ----------------
__global__ __launch_bounds__(256) void head_mfma(const float* __restrict__ X1,
                                                 const float* __restrict__ X2,
                                                 const float* __restrict__ X3,
                                                 const float* __restrict__ X4,
                                                 const ushort* __restrict__ w5h,
                                                 const ushort* __restrict__ w5l,
                                                 const float* __restrict__ wreg,
                                                 const float* __restrict__ g,
                                                 const float* __restrict__ bb,
                                                 const float* __restrict__ rm,
                                                 const float* __restrict__ rv,
                                                 float* __restrict__ partial) {
    __shared__ ushort Hh[128][40], Hl[128][40], Wh[128][40], Wl[128][40];
    __shared__ float sscale[128], srm[128], sbb[128], swreg[128];
    __shared__ float red[2][128];
    int tid = threadIdx.x;
    int lane = tid & 63, wid = tid >> 6;
    int wr = wid >> 1, wc = wid & 1;
    int o0 = blockIdx.x * 128;
    int p0 = blockIdx.y * 128;

    if (tid < 128) {
        int o = o0 + tid;
        sscale[tid] = g[o] / sqrtf(rv[o] + EPS);
        srm[tid] = rm[o]; sbb[tid] = bb[o]; swreg[tid] = wreg[o];
    }

    const int pt = tid >> 1;            // 0..127
    const int co = (tid & 1) * 16;      // {0,16}

    f32x4 z = {0.f, 0.f, 0.f, 0.f};
    f32x4 acc[4][4];
#pragma unroll
    for (int sr = 0; sr < 4; ++sr)
#pragma unroll
        for (int sc = 0; sc < 4; ++sc) acc[sr][sc] = z;

    for (int c0 = 0; c0 < 512; c0 += 32) {
        const float* src;
        int coff, Cs;
        if (c0 < 64)       { src = X1; coff = c0;       Cs = 64; }
        else if (c0 < 128) { src = X2; coff = c0 - 64;  Cs = 64; }
        else if (c0 < 256) { src = X3; coff = c0 - 128; Cs = 128; }
        else               { src = X4; coff = c0 - 256; Cs = 256; }
        const float* hp = &src[(size_t)(p0 + pt) * Cs + coff + co];
        float4 f0 = *(const float4*)&hp[0];
        float4 f1 = *(const float4*)&hp[4];
        float4 f2 = *(const float4*)&hp[8];
        float4 f3 = *(const float4*)&hp[12];
        size_t wrow = (size_t)(o0 + pt) * 512 + c0 + co;
        uint4 wh0 = *(const uint4*)&w5h[wrow];
        uint4 wh1 = *(const uint4*)&w5h[wrow + 8];
        uint4 wl0 = *(const uint4*)&w5l[wrow];
        uint4 wl1 = *(const uint4*)&w5l[wrow + 8];
        float hv[16] = {f0.x, f0.y, f0.z, f0.w, f1.x, f1.y, f1.z, f1.w,
                        f2.x, f2.y, f2.z, f2.w, f3.x, f3.y, f3.z, f3.w};
        ushort hb[16], lb[16];
#pragma unroll
        for (int q = 0; q < 16; ++q) {
            hb[q] = f2bf(hv[q]);
            float hf = __uint_as_float((unsigned)hb[q] << 16);
            lb[q] = f2bf(hv[q] - hf);
        }
        uint4 hh0 = {pack2(hb[0], hb[1]), pack2(hb[2], hb[3]), pack2(hb[4], hb[5]), pack2(hb[6], hb[7])};
        uint4 hh1 = {pack2(hb[8], hb[9]), pack2(hb[10], hb[11]), pack2(hb[12], hb[13]), pack2(hb[14], hb[15])};
        uint4 hl0 = {pack2(lb[0], lb[1]), pack2(lb[2], lb[3]), pack2(lb[4], lb[5]), pack2(lb[6], lb[7])};
        uint4 hl1 = {pack2(lb[8], lb[9]), pack2(lb[10], lb[11]), pack2(lb[12], lb[13]), pack2(lb[14], lb[15])};
        __syncthreads();                 // prior K-step's frag reads done
        *(uint4*)&Hh[pt][co] = hh0; *(uint4*)&Hh[pt][co + 8] = hh1;
        *(uint4*)&Hl[pt][co] = hl0; *(uint4*)&Hl[pt][co + 8] = hl1;
        *(uint4*)&Wh[pt][co] = wh0; *(uint4*)&Wh[pt][co + 8] = wh1;
        *(uint4*)&Wl[pt][co] = wl0; *(uint4*)&Wl[pt][co + 8] = wl1;
        __syncthreads();
        bf16x8 ah[4], al[4], bh[4], bl[4];
#pragma unroll
        for (int s = 0; s < 4; ++s) {
            int orow = wr * 64 + s * 16 + (lane & 15);
            int prow = wc * 64 + s * 16 + (lane & 15);
            int ko = (lane >> 4) * 8;
            ah[s] = *(const bf16x8*)&Wh[orow][ko];
            al[s] = *(const bf16x8*)&Wl[orow][ko];
            bh[s] = *(const bf16x8*)&Hh[prow][ko];
            bl[s] = *(const bf16x8*)&Hl[prow][ko];
        }
#pragma unroll
        for (int sr = 0; sr < 4; ++sr)
#pragma unroll
            for (int sc = 0; sc < 4; ++sc) {
                acc[sr][sc] = __builtin_amdgcn_mfma_f32_16x16x32_bf16(ah[sr], bh[sc], acc[sr][sc], 0, 0, 0);
                acc[sr][sc] = __builtin_amdgcn_mfma_f32_16x16x32_bf16(ah[sr], bl[sc], acc[sr][sc], 0, 0, 0);
                acc[sr][sc] = __builtin_amdgcn_mfma_f32_16x16x32_bf16(al[sr], bh[sc], acc[sr][sc], 0, 0, 0);
                acc[sr][sc] = __builtin_amdgcn_mfma_f32_16x16x32_bf16(al[sr], bl[sc], acc[sr][sc], 0, 0, 0);
            }
    }

    float psum[4] = {0.f, 0.f, 0.f, 0.f};     // per sc
#pragma unroll
    for (int sr = 0; sr < 4; ++sr)
#pragma unroll
        for (int reg = 0; reg < 4; ++reg) {
            int ol = wr * 64 + sr * 16 + (lane >> 4) * 4 + reg;
            float scale = sscale[ol], smv = srm[ol], sbv = sbb[ol], wrv = swreg[ol];
#pragma unroll
            for (int sc = 0; sc < 4; ++sc) {
                float y = (acc[sr][sc][reg] - smv) * scale + sbv;
                y = y > 0.f ? y : 0.2f * y;
                psum[sc] = fmaf(wrv, y, psum[sc]);
            }
        }
#pragma unroll
    for (int sc = 0; sc < 4; ++sc) {
        psum[sc] += __shfl_xor(psum[sc], 16);
        psum[sc] += __shfl_xor(psum[sc], 32);
    }
    if ((lane >> 4) == 0) {
#pragma unroll
        for (int sc = 0; sc < 4; ++sc)
            red[wr][wc * 64 + sc * 16 + lane] = psum[sc];
    }
    __syncthreads();
    if (tid < 128)
        partial[(size_t)blockIdx.x * PTS + p0 + tid] = red[0][tid] + red[1][tid];
}

// ---------------- head stage 2: out[p] = sum over 8 o-tiles ----------------
__global__ __launch_bounds__(256) void head_reduce(const float* __restrict__ partial,
                                                   float* __restrict__ out) {
    int p = blockIdx.x * 256 + threadIdx.x;
    if (p >= PTS) return;
    float s = 0.f;
#pragma unroll
    for (int q = 0; q < 8; ++q) s += partial[(size_t)q * PTS + p];
    out[p] = s;
}

extern "C" void kernel_launch(void* const* d_in, const int* in_sizes, int n_in,
                              void* d_out, int out_size, void* d_ws, size_t ws_size,
                              hipStream_t stream) {
    const float* x    = (const float*)d_in[0];
    const float* w1   = (const float*)d_in[1];
    const float* w2   = (const float*)d_in[2];
    const float* w3   = (const float*)d_in[3];
    const float* w4   = (const float*)d_in[4];
    const float* w5   = (const float*)d_in[5];
    const float* wreg = (const float*)d_in[6];
    const float* bn[5][4];
    for (int t = 0; t < 5; ++t)
        for (int q = 0; q < 4; ++q)
            bn[t][q] = (const float*)d_in[7 + t * 4 + q];
    float* out = (float*)d_out;

    // workspace layout (bytes), peak 195 MB (proven OK in pair mode).
    char* ws = (char*)d_ws;
    size_t o_x1  = 0;
    size_t o_x2  = o_x1  + (size_t)PTS * 64 * 4;
    size_t o_x3  = o_x2  + (size_t)PTS * 64 * 4;
    size_t o_x4  = o_x3  + (size_t)PTS * 128 * 4;
    size_t o_idx = o_x4  + (size_t)PTS * 256 * 4;
    size_t o_xx  = o_idx + (size_t)PTS * 20 * 4;
    size_t o_pd  = o_xx  + (size_t)PTS * 4;
    size_t o_u   = o_pd;                            // alias: U over PD slab
    size_t pdslab = (size_t)NPT * NPT * 4;          // 64 MB

    float* X1 = (float*)(ws + o_x1);
    float* X2 = (float*)(ws + o_x2);
    float* X3 = (float*)(ws + o_x3);
    float* X4 = (float*)(ws + o_x4);
    int*   IDX = (int*)(ws + o_idx);
    float* XX = (float*)(ws + o_xx);
    float* PD = (float*)(ws + o_pd);
    float* U  = (float*)(ws + o_u);
    float* T  = (float*)(ws + o_u + (size_t)PTS * 256 * 4);
    float* PART = (float*)(ws + o_idx);             // 1 MB < IDX slab
    ushort* XH = (ushort*)(ws + o_x4);              // bf16 hi plane (<=8 MB)
    ushort* XL = (ushort*)(ws + o_x4 + (size_t)PTS * 128 * 2);  // lo plane
    ushort* W5H = (ushort*)(ws + o_u);              // w5 planes alias U (dead at head)
    ushort* W5L = W5H + (size_t)1024 * 512;

    const bool pair = ws_size >= o_pd + 2 * pdslab;
    const int bstep = pair ? 2 : 1;
    const size_t pdstride = pair ? (size_t)NPT * NPT : 0;   // floats

    auto knn_layer = [&](int C) {
        for (int b = 0; b < BATCH; b += bstep) {
            pd_mfma<<<dim3(528, bstep), 256, 0, stream>>>(XH, XL, XX, PD, C, b, pdstride);
            topk20<<<dim3(NPT / 4, bstep), 256, 0, stream>>>(PD, IDX, b, pdstride);
        }
    };

    // ---- layer 1 (C=1 -> O=64) ----
    sqnorm<<<PTS / 256, 256, 0, stream>>>(x, XX, 1);
    topk1<<<dim3(NPT / 4, BATCH), 256, 0, stream>>>(x, XX, IDX);
    ut1<<<PTS / 4, 256, 0, stream>>>(x, w1, U, T);
    gather_max4<<<PTS * 16 / 256, 256, 0, stream>>>(U, T, IDX,
            bn[0][0], bn[0][1], bn[0][2], bn[0][3], X1, 64);

    // ---- layer 2 (C=64 -> O=64) ----
    sqnorm_cvt<<<PTS / 256, 256, 0, stream>>>(X1, XX, XH, XL, 64);
    knn_layer(64);
    ut_gemm<<<dim3(PTS / 64, 1), 256, 0, stream>>>(X1, w2, U, T, 64, 64);
    gather_max4<<<PTS * 16 / 256, 256, 0, stream>>>(U, T, IDX,
            bn[1][0], bn[1][1], bn[1][2], bn[1][3], X2, 64);

    // ---- layer 3 (C=64 -> O=128) ----
    sqnorm_cvt<<<PTS / 256, 256, 0, stream>>>(X2, XX, XH, XL, 64);
    knn_layer(64);
    ut_gemm<<<dim3(PTS / 64, 2), 256, 0, stream>>>(X2, w3, U, T, 64, 128);
    gather_max4<<<PTS * 32 / 256, 256, 0, stream>>>(U, T, IDX,
            bn[2][0], bn[2][1], bn[2][2], bn[2][3], X3, 128);

    // ---- layer 4 (C=128 -> O=256) ----
    sqnorm_cvt<<<PTS / 256, 256, 0, stream>>>(X3, XX, XH, XL, 128);
    knn_layer(128);
    ut_gemm<<<dim3(PTS / 64, 4), 256, 0, stream>>>(X3, w4, U, T, 128, 256);
    gather_max4<<<PTS * 64 / 256, 256, 0, stream>>>(U, T, IDX,
            bn[3][0], bn[3][1], bn[3][2], bn[3][3], X4, 256);

    // ---- fused head (MFMA) ----
    w5cvt<<<512, 256, 0, stream>>>(w5, W5H, W5L);
    head_mfma<<<dim3(8, PTS / 128), 256, 0, stream>>>(X1, X2, X3, X4, W5H, W5L,
            wreg, bn[4][0], bn[4][1], bn[4][2], bn[4][3], PART);
    head_reduce<<<PTS / 256, 256, 0, stream>>>(PART, out);
}